// Round 8
// baseline (6791.242 us; speedup 1.0000x reference)
//
#include <hip/hip_runtime.h>

// ============================================================================
// RSSM (DynamicsModel) on MI355X — round 8.
// Diagnosis r7: kernels are LLC-BW bound; 128-row tiles streamed every weight
// TWICE per step (M=256 -> 2 M-blocks) + 50 MB fp32 partial traffic = ~250
// MB/step.  Fix:
//   * gemm_n64: M=256(whole)xN=64 tile, BK=64, 80KB LDS -> weights read ONCE
//   * gi/gh outputs bf16 (25->12.6 MB rt); split-K partials bf16 (33->16 MB)
//   * traffic/step ~250 -> ~115 MB
// Trunk: 7 dispatches/step (gaps measured cheap); proven 128^2 kernel kept
// for the two batched precomputes.
// ============================================================================

typedef __attribute__((ext_vector_type(8))) short bf16x8;
typedef __attribute__((ext_vector_type(4))) float f32x4;
typedef __attribute__((ext_vector_type(4))) short s16x4;

#define DEVI static __device__ __forceinline__

DEVI float bf2f(short s) { union { float f; unsigned u; } v; v.u = ((unsigned)(unsigned short)s) << 16; return v.f; }
DEVI short f2bf(float f) {
  union { float f; unsigned u; } v; v.f = f;
  unsigned r = v.u + 0x7FFFu + ((v.u >> 16) & 1u);   // RNE
  return (short)(r >> 16);
}

#define Bsz 256
#define Tsz 64
#define Hsz 2048
#define Ssz 512
#define Asz 64
#define Esz 2048
#define TM1 63

#define PSHB (256 * 2048)   // bf16 partial stride (elems)
#define PSSB (256 * 1024)

#define OUT_PS  33554432L
#define OUT_QS  41943040L
#define OUT_PM  50331648L
#define OUT_PLV 58589184L
#define OUT_QM  66846720L
#define OUT_QLV 75104256L

struct GArg {
  const short* A; const short* Bt; const float* bias; const short* Ci;
  float* oF; short* oB;
  int lda, ldb, ldoF, ldoB; long ldci, pstride;
};

// ---------------------------------------------------------------------------
// Traffic-optimal scan GEMM: C[256,N] = A[256,K] @ Bt[N,K]^T.
// Tile 256(all M) x 64(N), BK=64.  4 waves, wave = 64 rows x 64 cols
// (4mi x 4ni frags).  LDS 80 KB (A 64K dbuf + B 16K dbuf), 10 loads/wave/
// stage, vmcnt(10).  XOR-swizzle via pre-swizzled source (proven r2).
// blockIdx.x = n-block; blockIdx.z: gemm = glog?(z&1):0, kc = z>>glog.
// ---------------------------------------------------------------------------
template<int HASBIAS, int HASCI, int RELU, int OUTF, int OUTB>
__global__ __launch_bounds__(256) void gemm_n64(GArg g0, GArg g1, int glog, int kcK) {
  const int z = blockIdx.z;
  const int gemm = glog ? (z & 1) : 0;
  const int kc = z >> glog;
  const GArg g = gemm ? g1 : g0;
  const short* __restrict__ Ag = g.A + (long)kc * kcK;
  const short* __restrict__ Bg = g.Bt + (long)kc * kcK;
  __shared__ __align__(16) short As[2][16384];   // 256x64 dbuf = 64 KB
  __shared__ __align__(16) short Bs[2][4096];    //  64x64 dbuf = 16 KB
  const int tid = threadIdx.x;
  const int w = tid >> 6, l = tid & 63;
  const int bn0 = blockIdx.x << 6;
  const int fc = l & 15, fh = l >> 4;
  const int wr = w << 6;                         // wave's 64-row slice
  const int rx = fc & 7;
  const int srccol = ((l & 7) ^ ((l >> 3) & 7)) << 3;

  long aoff[8], boff[2];
#pragma unroll
  for (int i = 0; i < 8; ++i) {
    const int row = (((i << 2) + w) << 3) + (l >> 3);    // 0..255
    aoff[i] = (long)row * g.lda + srccol;
  }
#pragma unroll
  for (int i = 0; i < 2; ++i) {
    const int row = (((i << 2) + w) << 3) + (l >> 3);    // 0..63
    boff[i] = (long)(bn0 + row) * g.ldb + srccol;
  }

  f32x4 acc[4][4];
#pragma unroll
  for (int i = 0; i < 4; ++i)
#pragma unroll
    for (int j = 0; j < 4; ++j) acc[i][j] = f32x4{0.f, 0.f, 0.f, 0.f};

  auto STAGE = [&](int kt, int buf) {
#pragma unroll
    for (int i = 0; i < 8; ++i) {
      const int ib = ((i << 2) + w) << 10;
      __builtin_amdgcn_global_load_lds(
          (const __attribute__((address_space(1))) void*)(Ag + aoff[i] + (kt << 6)),
          (__attribute__((address_space(3))) void*)((char*)&As[buf][0] + ib), 16, 0, 0);
    }
#pragma unroll
    for (int i = 0; i < 2; ++i) {
      const int ib = ((i << 2) + w) << 10;
      __builtin_amdgcn_global_load_lds(
          (const __attribute__((address_space(1))) void*)(Bg + boff[i] + (kt << 6)),
          (__attribute__((address_space(3))) void*)((char*)&Bs[buf][0] + ib), 16, 0, 0);
    }
  };
  auto COMPUTE = [&](int buf) {
#pragma unroll
    for (int kk = 0; kk < 2; ++kk) {
      const int sw = (((kk << 2) + fh) ^ rx) << 3;
      bf16x8 af[4], bb[4];
#pragma unroll
      for (int mi = 0; mi < 4; ++mi)
        af[mi] = *(const bf16x8*)&As[buf][(wr + (mi << 4) + fc) * 64 + sw];
#pragma unroll
      for (int ni = 0; ni < 4; ++ni)
        bb[ni] = *(const bf16x8*)&Bs[buf][((ni << 4) + fc) * 64 + sw];
#pragma unroll
      for (int mi = 0; mi < 4; ++mi)
#pragma unroll
        for (int ni = 0; ni < 4; ++ni)
          acc[mi][ni] = __builtin_amdgcn_mfma_f32_16x16x32_bf16(af[mi], bb[ni], acc[mi][ni], 0, 0, 0);
    }
  };

  const int nk = kcK >> 6;
  STAGE(0, 0);
  for (int kt = 0; kt < nk - 1; ++kt) {
    STAGE(kt + 1, (kt + 1) & 1);
    asm volatile("s_waitcnt vmcnt(10)" ::: "memory");
    __builtin_amdgcn_s_barrier();
    __builtin_amdgcn_sched_barrier(0);
    COMPUTE(kt & 1);
    asm volatile("s_waitcnt lgkmcnt(0)" ::: "memory");
    __builtin_amdgcn_s_barrier();
  }
  asm volatile("s_waitcnt vmcnt(0)" ::: "memory");
  __builtin_amdgcn_s_barrier();
  __builtin_amdgcn_sched_barrier(0);
  COMPUTE((nk - 1) & 1);

  float* oF = OUTF ? (g.oF + (long)kc * g.pstride) : (float*)nullptr;
  short* oB = OUTB ? (g.oB + (long)kc * g.pstride) : (short*)nullptr;
#pragma unroll
  for (int mi = 0; mi < 4; ++mi) {
#pragma unroll
    for (int ni = 0; ni < 4; ++ni) {
      const int n = bn0 + (ni << 4) + fc;
      float bv = 0.f;
      if (HASBIAS) bv = g.bias[n];
#pragma unroll
      for (int r = 0; r < 4; ++r) {
        const int m = wr + (mi << 4) + (fh << 2) + r;
        float v = acc[mi][ni][r] + bv;
        if (HASCI) v += bf2f(g.Ci[(long)m * g.ldci + n]);
        if (RELU) v = fmaxf(v, 0.f);
        if (OUTF) oF[(long)m * g.ldoF + n] = v;
        if (OUTB) oB[(long)m * g.ldoB + n] = f2bf(v);
      }
    }
  }
}

// ---------------------------------------------------------------------------
// throughput GEMM for batched precomputes (proven r2): 128x128, BK=64.
// ---------------------------------------------------------------------------
template<int HASBIAS, int HASCI, int RELU, int OUTF, int OUTB>
__global__ __launch_bounds__(256) void gemm_bt(GArg g0, GArg g1, int kcK) {
  const int gemm = blockIdx.z & 1;
  const GArg g = gemm ? g1 : g0;
  const short* __restrict__ Ag = g.A;
  const short* __restrict__ Bg = g.Bt;
  __shared__ __align__(16) short As[2][8192];
  __shared__ __align__(16) short Bs[2][8192];
  const int tid = threadIdx.x;
  const int w = tid >> 6, l = tid & 63;
  const int bm0 = blockIdx.y << 7, bn0 = blockIdx.x << 7;
  const int fc = l & 15, fh = l >> 4;
  const int wr = (w >> 1) << 6, wc = (w & 1) << 6;
  const int rx = fc & 7;
  const int srccol = ((l & 7) ^ ((l >> 3) & 7)) << 3;
  long aoff[4], boff[4];
#pragma unroll
  for (int i = 0; i < 4; ++i) {
    const int row = (((i << 2) + w) << 3) + (l >> 3);
    aoff[i] = (long)(bm0 + row) * g.lda + srccol;
    boff[i] = (long)(bn0 + row) * g.ldb + srccol;
  }
  f32x4 acc[4][4];
#pragma unroll
  for (int i = 0; i < 4; ++i)
#pragma unroll
    for (int j = 0; j < 4; ++j) acc[i][j] = f32x4{0.f, 0.f, 0.f, 0.f};

  auto STAGE = [&](int kt, int buf) {
#pragma unroll
    for (int i = 0; i < 4; ++i) {
      const int ib = ((i << 2) + w) << 10;
      __builtin_amdgcn_global_load_lds(
          (const __attribute__((address_space(1))) void*)(Ag + aoff[i] + (kt << 6)),
          (__attribute__((address_space(3))) void*)((char*)&As[buf][0] + ib), 16, 0, 0);
      __builtin_amdgcn_global_load_lds(
          (const __attribute__((address_space(1))) void*)(Bg + boff[i] + (kt << 6)),
          (__attribute__((address_space(3))) void*)((char*)&Bs[buf][0] + ib), 16, 0, 0);
    }
  };
  auto COMPUTE = [&](int buf) {
#pragma unroll
    for (int kk = 0; kk < 2; ++kk) {
      bf16x8 af[4], bb[4];
#pragma unroll
      for (int mi = 0; mi < 4; ++mi)
        af[mi] = *(const bf16x8*)&As[buf][(wr + (mi << 4) + fc) * 64 + ((((kk << 2) + fh) ^ rx) << 3)];
#pragma unroll
      for (int ni = 0; ni < 4; ++ni)
        bb[ni] = *(const bf16x8*)&Bs[buf][(wc + (ni << 4) + fc) * 64 + ((((kk << 2) + fh) ^ rx) << 3)];
#pragma unroll
      for (int mi = 0; mi < 4; ++mi)
#pragma unroll
        for (int ni = 0; ni < 4; ++ni)
          acc[mi][ni] = __builtin_amdgcn_mfma_f32_16x16x32_bf16(af[mi], bb[ni], acc[mi][ni], 0, 0, 0);
    }
  };

  const int nk = kcK >> 6;
  STAGE(0, 0);
  for (int kt = 0; kt < nk - 1; ++kt) {
    STAGE(kt + 1, (kt + 1) & 1);
    asm volatile("s_waitcnt vmcnt(8)" ::: "memory");
    __builtin_amdgcn_s_barrier();
    __builtin_amdgcn_sched_barrier(0);
    COMPUTE(kt & 1);
    asm volatile("s_waitcnt lgkmcnt(0)" ::: "memory");
    __builtin_amdgcn_s_barrier();
  }
  asm volatile("s_waitcnt vmcnt(0)" ::: "memory");
  __builtin_amdgcn_s_barrier();
  __builtin_amdgcn_sched_barrier(0);
  COMPUTE((nk - 1) & 1);

#pragma unroll
  for (int mi = 0; mi < 4; ++mi) {
#pragma unroll
    for (int ni = 0; ni < 4; ++ni) {
      const int n = bn0 + wc + (ni << 4) + fc;
      float bv = 0.f;
      if (HASBIAS) bv = g.bias[n];
#pragma unroll
      for (int r = 0; r < 4; ++r) {
        const int m = bm0 + wr + (mi << 4) + (fh << 2) + r;
        float v = acc[mi][ni][r] + bv;
        if (HASCI) v += bf2f(g.Ci[(long)m * g.ldci + n]);
        if (RELU) v = fmaxf(v, 0.f);
        if (OUTF) g.oF[(long)m * g.ldoF + n] = v;
        if (OUTB) g.oB[(long)m * g.ldoB + n] = f2bf(v);
      }
    }
  }
}

// ---------------------------------------------------------------------------
// small kernels
// ---------------------------------------------------------------------------
__global__ void conv_f2b(const float* __restrict__ src, short* __restrict__ dst, long n) {
  long i = ((long)blockIdx.x * 256 + threadIdx.x) * 4;
  const long stride = (long)gridDim.x * 1024;
  for (; i < n; i += stride) {
    float4 v = *(const float4*)(src + i);
    s16x4 o;
    o[0] = f2bf(v.x); o[1] = f2bf(v.y); o[2] = f2bf(v.z); o[3] = f2bf(v.w);
    *(s16x4*)(dst + i) = o;
  }
}

__global__ void transp(const float* __restrict__ src, short* __restrict__ dst,
                       int srcld, int k0, int K, int N) {
  __shared__ float t[32][33];
  const int tx = threadIdx.x, ty = threadIdx.y;
  const int kb = blockIdx.y << 5, nb = blockIdx.x << 5;
#pragma unroll
  for (int i = ty; i < 32; i += 8)
    t[i][tx] = src[(long)(k0 + kb + i) * srcld + nb + tx];
  __syncthreads();
#pragma unroll
  for (int i = ty; i < 32; i += 8)
    dst[(long)(nb + i) * K + kb + tx] = f2bf(t[tx][i]);
}

__global__ void init_kernel(const float* __restrict__ ph, const float* __restrict__ ps,
                            float* __restrict__ out, short* __restrict__ hb, short* __restrict__ sb) {
  const int idx = blockIdx.x * 256 + threadIdx.x;
  const int b = idx >> 11, n = idx & 2047;
  const float h = ph[idx];
  out[(long)b * (Tsz * Hsz) + n] = h;
  hb[idx] = f2bf(h);
  if (n < Ssz) {
    const int sidx = b * Ssz + n;
    const float s = ps[sidx];
    out[OUT_PS + (long)b * (Tsz * Ssz) + n] = s;
    out[OUT_QS + (long)b * (Tsz * Ssz) + n] = s;
    sb[sidx] = f2bf(s);
  }
}

// GRU fusion (bf16 gate inputs).
__global__ void gru_kernel(const short* __restrict__ gi, const short* __restrict__ gh,
                           const float* __restrict__ b_ih, const float* __restrict__ b_hh,
                           const float* __restrict__ hold, float* __restrict__ hnew,
                           short* __restrict__ hb) {
  const int i4 = (blockIdx.x * 256 + threadIdx.x) * 4;   // grid 512
  const int b = i4 >> 11, n = i4 & 2047;
  const long gb = (long)b * (3 * Hsz) + n;
  const s16x4 vir = *(const s16x4*)&gi[gb];
  const s16x4 viz = *(const s16x4*)&gi[gb + Hsz];
  const s16x4 vin = *(const s16x4*)&gi[gb + 2 * Hsz];
  const s16x4 vhr = *(const s16x4*)&gh[gb];
  const s16x4 vhz = *(const s16x4*)&gh[gb + Hsz];
  const s16x4 vhn = *(const s16x4*)&gh[gb + 2 * Hsz];
  const float4 ho = *(const float4*)&hold[(long)b * (Tsz * Hsz) + n];
  const float* hop = (const float*)&ho;
  float4 hv; float* hvp = (float*)&hv;
  s16x4 hbv;
#pragma unroll
  for (int e = 0; e < 4; ++e) {
    const int ne = n + e;
    const float ir = bf2f(vir[e]) + b_ih[ne],           hr = bf2f(vhr[e]) + b_hh[ne];
    const float iz = bf2f(viz[e]) + b_ih[Hsz + ne],     hz = bf2f(vhz[e]) + b_hh[Hsz + ne];
    const float in_ = bf2f(vin[e]) + b_ih[2 * Hsz + ne];
    const float hn = bf2f(vhn[e]) + b_hh[2 * Hsz + ne];
    const float r = 1.f / (1.f + expf(-(ir + hr)));
    const float zz = 1.f / (1.f + expf(-(iz + hz)));
    const float nn = tanhf(in_ + r * hn);
    const float h = (1.f - zz) * nn + zz * hop[e];
    hvp[e] = h;
    hbv[e] = f2bf(h);
  }
  *(float4*)&hnew[(long)b * (Tsz * Hsz) + n] = hv;
  *(s16x4*)&hb[i4] = hbv;
}

// reduce 4 bf16 partials + ci, relu -> bf16
__global__ void reduce_relu4(const short* __restrict__ p, const short* __restrict__ ciA,
                             const short* __restrict__ ciB, short* __restrict__ oA,
                             short* __restrict__ oB, int t) {
  const int z = blockIdx.y;
  const short* pz = p + (long)z * 4 * PSHB;
  const short* ci = z ? ciB : ciA;
  short* o = z ? oB : oA;
  const int i = (blockIdx.x * 256 + threadIdx.x) * 4;
  const int b = i >> 11, n = i & 2047;
  float v[4] = {0.f, 0.f, 0.f, 0.f};
#pragma unroll
  for (int k = 0; k < 4; ++k) {
    const s16x4 pk = *(const s16x4*)&pz[(long)k * PSHB + i];
#pragma unroll
    for (int e = 0; e < 4; ++e) v[e] += bf2f(pk[e]);
  }
  const s16x4 c = *(const s16x4*)&ci[((long)b * Tsz + t) * Hsz + n];
  s16x4 ov;
#pragma unroll
  for (int e = 0; e < 4; ++e) ov[e] = f2bf(fmaxf(v[e] + bf2f(c[e]), 0.f));
  *(s16x4*)&o[i] = ov;
}

// reduce bf16 pr/po partials + bias, rsample, write outputs
__global__ void sample_kernel(const short* __restrict__ pp,
                              const float* __restrict__ bp, const float* __restrict__ bq,
                              const float* __restrict__ pn, const float* __restrict__ qn,
                              float* __restrict__ out, short* __restrict__ sb, int t) {
  const int idx = blockIdx.x * 256 + threadIdx.x;
  const int b = idx >> 9, j = idx & 511;
  const short* pr = pp;
  const short* po = pp + 4L * PSSB;
  const long r0 = (long)b * 1024 + j;
  float pm = bp[j], plv = bp[512 + j], qm = bq[j], qlv = bq[512 + j];
#pragma unroll
  for (int k = 0; k < 4; ++k) {
    pm  += bf2f(pr[k * PSSB + r0]);  plv += bf2f(pr[k * PSSB + r0 + 512]);
    qm  += bf2f(po[k * PSSB + r0]);  qlv += bf2f(po[k * PSSB + r0 + 512]);
  }
  const long noff = ((long)b * TM1 + t) * Ssz + j;
  const float psv = pm + (1.f + expf(plv)) * pn[noff];
  const float qsv = qm + (1.f + expf(qlv)) * qn[noff];
  out[OUT_PS + (long)b * (Tsz * Ssz) + (long)(t + 1) * Ssz + j] = psv;
  out[OUT_QS + (long)b * (Tsz * Ssz) + (long)(t + 1) * Ssz + j] = qsv;
  out[OUT_PM  + noff] = pm;
  out[OUT_PLV + noff] = plv;
  out[OUT_QM  + noff] = qm;
  out[OUT_QLV + noff] = qlv;
  sb[idx] = f2bf(qsv);
}

static GArg mk(const short* A, int lda, const short* Bt, int ldb, const float* bias,
               const short* Ci, long ldci, float* oF, int ldoF, long pstride,
               short* oB, int ldoB) {
  GArg g; g.A = A; g.Bt = Bt; g.bias = bias; g.Ci = Ci; g.ldci = ldci;
  g.oF = oF; g.oB = oB; g.lda = lda; g.ldb = ldb; g.ldoF = ldoF; g.ldoB = ldoB;
  g.pstride = pstride;
  return g;
}

extern "C" void kernel_launch(void* const* d_in, const int* in_sizes, int n_in,
                              void* d_out, int out_size, void* d_ws, size_t ws_size,
                              hipStream_t stream) {
  const float* prev_hidden = (const float*)d_in[0];
  const float* prev_state  = (const float*)d_in[1];
  const float* actions     = (const float*)d_in[2];
  const float* obs         = (const float*)d_in[3];
  const float* prior_noise = (const float*)d_in[4];
  const float* post_noise  = (const float*)d_in[5];
  const float* W_sa = (const float*)d_in[6];
  const float* b_sa = (const float*)d_in[7];
  const float* W_ih = (const float*)d_in[8];
  const float* W_hh = (const float*)d_in[9];
  const float* b_ih = (const float*)d_in[10];
  const float* b_hh = (const float*)d_in[11];
  const float* W_ha = (const float*)d_in[12];
  const float* b_ha = (const float*)d_in[13];
  const float* W_prior = (const float*)d_in[14];
  const float* b_prior = (const float*)d_in[15];
  const float* W_ho = (const float*)d_in[16];
  const float* b_ho = (const float*)d_in[17];
  const float* W_post = (const float*)d_in[18];
  const float* b_post = (const float*)d_in[19];
  float* out = (float*)d_out;

  char* p = (char*)d_ws;
  auto alloc = [&](size_t bytes) { char* r = p; p += (bytes + 255) & ~(size_t)255; return r; };
  short* Wih_b   = (short*)alloc(3L * Hsz * Hsz * 2);
  short* Whh_b   = (short*)alloc(3L * Hsz * Hsz * 2);
  short* Wt_sa_s = (short*)alloc((long)Hsz * Ssz * 2);
  short* Wt_sa_a = (short*)alloc((long)Hsz * Asz * 2);
  short* Wt_ha_h = (short*)alloc((long)Hsz * Hsz * 2);
  short* Wt_ha_a = (short*)alloc((long)Hsz * Asz * 2);
  short* Wt_ho_h = (short*)alloc((long)Hsz * Hsz * 2);
  short* Wt_ho_o = (short*)alloc((long)Hsz * Esz * 2);
  short* Wt_pr   = (short*)alloc(2L * Ssz * Hsz * 2);
  short* Wt_po   = (short*)alloc(2L * Ssz * Hsz * 2);
  short* obs_b   = (short*)alloc((long)Bsz * Tsz * Esz * 2);   // 64 MB, aliased below
  short* act_b   = (short*)alloc((long)Bsz * Tsz * Asz * 2);
  short* a_pre   = (short*)alloc((long)Bsz * Tsz * Hsz * 2);
  short* ha_a    = (short*)alloc((long)Bsz * Tsz * Hsz * 2);
  short* ho_o    = (short*)alloc((long)Bsz * Tsz * Hsz * 2);
  short* s_b     = (short*)alloc((long)Bsz * Ssz * 2);
  short* h_b     = (short*)alloc((long)Bsz * Hsz * 2);
  short* sa_b    = (short*)alloc((long)Bsz * Hsz * 2);
  short* ha_b    = (short*)alloc((long)Bsz * Hsz * 2);
  short* ho_b    = (short*)alloc((long)Bsz * Hsz * 2);
  char* q = (char*)obs_b;                     // alias region (dead after precompute)
  auto alias = [&](size_t bytes) { char* r = q; q += (bytes + 255) & ~(size_t)255; return r; };
  short* gi_b    = (short*)alias((long)Bsz * 3 * Hsz * 2);   // 3 MB
  short* gh_b    = (short*)alias((long)Bsz * 3 * Hsz * 2);
  short* haho_pb = (short*)alias(8L * PSHB * 2);             // 8 MB
  short* prpo_pb = (short*)alias(8L * PSSB * 2);             // 4 MB
  (void)ws_size; (void)in_sizes; (void)n_in; (void)out_size;

  // ---- setup ----------------------------------------------------------------
  conv_f2b<<<4096, 256, 0, stream>>>(obs,  obs_b, (long)Bsz * Tsz * Esz);
  conv_f2b<<<1024, 256, 0, stream>>>(actions, act_b, (long)Bsz * Tsz * Asz);
  conv_f2b<<<4096, 256, 0, stream>>>(W_ih, Wih_b, 3L * Hsz * Hsz);
  conv_f2b<<<4096, 256, 0, stream>>>(W_hh, Whh_b, 3L * Hsz * Hsz);

  dim3 tb(32, 8);
  transp<<<dim3(Hsz / 32, Ssz / 32), tb, 0, stream>>>(W_sa, Wt_sa_s, Hsz, 0,   Ssz, Hsz);
  transp<<<dim3(Hsz / 32, Asz / 32), tb, 0, stream>>>(W_sa, Wt_sa_a, Hsz, Ssz, Asz, Hsz);
  transp<<<dim3(Hsz / 32, Hsz / 32), tb, 0, stream>>>(W_ha, Wt_ha_h, Hsz, 0,   Hsz, Hsz);
  transp<<<dim3(Hsz / 32, Asz / 32), tb, 0, stream>>>(W_ha, Wt_ha_a, Hsz, Hsz, Asz, Hsz);
  transp<<<dim3(Hsz / 32, Hsz / 32), tb, 0, stream>>>(W_ho, Wt_ho_h, Hsz, 0,   Hsz, Hsz);
  transp<<<dim3(Hsz / 32, Esz / 32), tb, 0, stream>>>(W_ho, Wt_ho_o, Hsz, Hsz, Esz, Hsz);
  transp<<<dim3(2 * Ssz / 32, Hsz / 32), tb, 0, stream>>>(W_prior, Wt_pr, 2 * Ssz, 0, Hsz, 2 * Ssz);
  transp<<<dim3(2 * Ssz / 32, Hsz / 32), tb, 0, stream>>>(W_post,  Wt_po, 2 * Ssz, 0, Hsz, 2 * Ssz);

  init_kernel<<<2048, 256, 0, stream>>>(prev_hidden, prev_state, out, h_b, s_b);

  // t-independent precomputes (before scan: scan aliases obs_b region)
  {
    GArg g0 = mk(act_b, Asz, Wt_sa_a, Asz, b_sa, nullptr, 0, nullptr, 0, 0, a_pre, Hsz);
    GArg g1 = mk(act_b, Asz, Wt_ha_a, Asz, b_ha, nullptr, 0, nullptr, 0, 0, ha_a, Hsz);
    gemm_bt<1, 0, 0, 0, 1><<<dim3(Hsz / 128, (Bsz * Tsz) / 128, 2), 256, 0, stream>>>(g0, g1, Asz);
  }
  {
    GArg g0 = mk(obs_b, Esz, Wt_ho_o, Esz, b_ho, nullptr, 0, nullptr, 0, 0, ho_o, Hsz);
    gemm_bt<1, 0, 0, 0, 1><<<dim3(Hsz / 128, (Bsz * Tsz) / 128, 1), 256, 0, stream>>>(g0, g0, Esz);
  }

  // ---- sequential scan: 7 dispatches / step (traffic-optimal tiles) --------
  const long ldPre = (long)Tsz * Hsz;
  for (int t = 0; t < TM1; ++t) {
    // 1) sa = relu(s @ Wsa_s^T + a_pre[t])          [256,2048] K=512, 32 blks
    {
      GArg g0 = mk(s_b, Ssz, Wt_sa_s, Ssz, nullptr, a_pre + (long)t * Hsz, ldPre,
                   nullptr, 0, 0, sa_b, Hsz);
      gemm_n64<0, 1, 1, 0, 1><<<dim3(32, 1, 1), 256, 0, stream>>>(g0, g0, 0, Ssz);
    }
    // 2) gi = sa @ Wih^T ; gh = h @ Whh^T (bf16)    [256,6144] K=2048, 192 blks
    {
      GArg g0 = mk(sa_b, Hsz, Wih_b, Hsz, nullptr, nullptr, 0, nullptr, 0, 0, gi_b, 3 * Hsz);
      GArg g1 = mk(h_b,  Hsz, Whh_b, Hsz, nullptr, nullptr, 0, nullptr, 0, 0, gh_b, 3 * Hsz);
      gemm_n64<0, 0, 0, 0, 1><<<dim3(96, 1, 2), 256, 0, stream>>>(g0, g1, 1, Hsz);
    }
    // 3) GRU
    gru_kernel<<<512, 256, 0, stream>>>(gi_b, gh_b, b_ih, b_hh,
                                        out + (long)t * Hsz, out + (long)(t + 1) * Hsz, h_b);
    // 4) ha/ho bf16 partials, split-K4              [256,2048] K=2048, 256 blks
    {
      GArg g0 = mk(h_b, Hsz, Wt_ha_h, Hsz, nullptr, nullptr, 0, nullptr, 0, PSHB, haho_pb, Hsz);
      GArg g1 = mk(h_b, Hsz, Wt_ho_h, Hsz, nullptr, nullptr, 0, nullptr, 0, PSHB, haho_pb + 4L * PSHB, Hsz);
      gemm_n64<0, 0, 0, 0, 1><<<dim3(32, 1, 8), 256, 0, stream>>>(g0, g1, 1, Hsz / 4);
    }
    // 5) reduce + relu -> ha_b / ho_b
    reduce_relu4<<<dim3(512, 2), 256, 0, stream>>>(haho_pb, ha_a, ho_o, ha_b, ho_b, t);
    // 6) prior/post bf16 partials, split-K4         [256,1024] K=2048, 128 blks
    {
      GArg g0 = mk(ha_b, Hsz, Wt_pr, Hsz, nullptr, nullptr, 0, nullptr, 0, PSSB, prpo_pb, 2 * Ssz);
      GArg g1 = mk(ho_b, Hsz, Wt_po, Hsz, nullptr, nullptr, 0, nullptr, 0, PSSB, prpo_pb + 4L * PSSB, 2 * Ssz);
      gemm_n64<0, 0, 0, 0, 1><<<dim3(16, 1, 8), 256, 0, stream>>>(g0, g1, 1, Hsz / 4);
    }
    // 7) reduce + rsample + outputs
    sample_kernel<<<512, 256, 0, stream>>>(prpo_pb, b_prior, b_post,
                                           prior_noise, post_noise, out, s_b, t);
  }
}